// Round 13
// baseline (171.808 us; speedup 1.0000x reference)
//
#include <hip/hip_runtime.h>

#define NN 100000
#define IC 128
#define OC 64
#define NE 1000000

#define NBUCK 256
#define BN 392          // nodes per bucket; 256*392 = 100352 >= NN
#define RCAP 4608       // bucket region capacity (mean 3906, +11 sigma)
#define EPB 2048        // edges per binning block
#define CAPA 24         // LDS buffer entries per bucket per block
#define GPAD 16         // gcur padding: one counter per 64B line
#define LDW 136         // epilogue LDS row stride (128 + 8 pad), ushorts
#define BINA_GRID 489   // ceil(NE/EPB)
#define CVT_BLOCKS 6250 // NN*IC/8/256

typedef __attribute__((ext_vector_type(8))) short short8;
typedef __attribute__((ext_vector_type(4))) float f32x4;

static __device__ __forceinline__ float b2f(unsigned short u) {
    unsigned v = ((unsigned)u) << 16;
    float f;
    __builtin_memcpy(&f, &v, 4);
    return f;
}
static __device__ __forceinline__ unsigned short f2b(float f) {
    unsigned u;
    __builtin_memcpy(&u, &f, 4);
    u += 0x7fff + ((u >> 16) & 1);
    return (unsigned short)(u >> 16);
}

// ---------------- fp8 e4m3 encode/decode (hw cvt if available, manual fallback) ----------------
#if defined(__has_builtin)
#if __has_builtin(__builtin_amdgcn_cvt_pk_fp8_f32) && __has_builtin(__builtin_amdgcn_cvt_pk_f32_fp8)
#define HW_FP8 1
#endif
#endif

static __device__ __forceinline__ unsigned f2q1(float f) {  // manual e4m3fn, FTZ
    unsigned u;
    __builtin_memcpy(&u, &f, 4);
    unsigned s = (u >> 24) & 0x80u;
    unsigned a = u & 0x7FFFFFFFu;
    if (a < 0x3C000000u) return s;
    if (a < 0x3C800000u) return s | 0x08u;
    if (a >= 0x43E00000u) return s | 0x7Eu;
    a += 0x7FFFFu + ((a >> 20) & 1u);
    unsigned e = (a >> 23) - 120u;
    unsigned m = (a >> 20) & 7u;
    unsigned c = (e << 3) | m;
    if (c > 0x7Eu) c = 0x7Eu;
    return s | c;
}
static __device__ __forceinline__ float q1f(unsigned q) {
    unsigned em = q & 0x7Fu;
    unsigned s = (q & 0x80u) << 24;
    unsigned u = (em >= 8u) ? (s | (((em >> 3) + 120u) << 23) | ((em & 7u) << 20)) : s;
    float f;
    __builtin_memcpy(&f, &u, 4);
    return f;
}

static __device__ __forceinline__ unsigned pack4_fp8(float a, float b, float c, float d) {
#ifdef HW_FP8
    int r = __builtin_amdgcn_cvt_pk_fp8_f32(a, b, 0, false);
    r = __builtin_amdgcn_cvt_pk_fp8_f32(c, d, r, true);
    return (unsigned)r;
#else
    return f2q1(a) | (f2q1(b) << 8) | (f2q1(c) << 16) | (f2q1(d) << 24);
#endif
}
static __device__ __forceinline__ void dec4(unsigned w, float* o) {
#ifdef HW_FP8
    auto p0 = __builtin_amdgcn_cvt_pk_f32_fp8((int)w, false);
    auto p1 = __builtin_amdgcn_cvt_pk_f32_fp8((int)w, true);
    o[0] = p0[0]; o[1] = p0[1]; o[2] = p1[0]; o[3] = p1[1];
#else
#pragma unroll
    for (int q = 0; q < 4; ++q) o[q] = q1f((w >> (8 * q)) & 0xFFu);
#endif
}

// ---------------- CSR pass A body: partition edges into 256 dst-range buckets ----------------
__device__ __forceinline__ void binA_body(int blk, int t,
                                          const int* __restrict__ src,
                                          const int* __restrict__ dst,
                                          int* __restrict__ gcur,
                                          unsigned* __restrict__ bins,
                                          unsigned (*buf)[CAPA], int* lcnt, int* goff) {
    lcnt[t] = 0;
    __syncthreads();
    const int e0 = blk * EPB;
#pragma unroll
    for (int q = 0; q < EPB / 256; ++q) {
        int e = e0 + q * 256 + t;
        if (e < NE) {
            int d = dst[e];
            int s = src[e];
            int b = d / BN;
            unsigned packed = ((unsigned)(d - b * BN) << 17) | (unsigned)s;
            int idx = atomicAdd(&lcnt[b], 1);
            if (idx < CAPA) {
                buf[b][idx] = packed;
            } else {
                int g = atomicAdd(&gcur[b * GPAD], 1);
                if (g < RCAP) bins[(size_t)b * RCAP + g] = packed;
            }
        }
    }
    __syncthreads();
    int c = lcnt[t];
    if (c > CAPA) c = CAPA;
    if (c > 0) goff[t] = atomicAdd(&gcur[t * GPAD], c);
    __syncthreads();
    const int wid = t >> 6, lane = t & 63;
    for (int b = wid * 64; b < wid * 64 + 64; ++b) {
        int cb = lcnt[b];
        if (cb > CAPA) cb = CAPA;
        if (lane < cb) {
            int g = goff[b] + lane;
            if (g < RCAP) bins[(size_t)b * RCAP + g] = buf[b][lane];
        }
    }
}

// ---------------- fused front kernel: binA | x->bf16+fp8 | weight prep ----------------
__global__ __launch_bounds__(256) void k_front(
    const int* __restrict__ src, const int* __restrict__ dst,
    int* __restrict__ gcur, unsigned* __restrict__ bins,
    const float* __restrict__ x, unsigned short* __restrict__ xb,
    unsigned char* __restrict__ xq,
    const float* __restrict__ W1l, const float* __restrict__ W1r,
    const float* __restrict__ Wml, const float* __restrict__ Wmr,
    const float* __restrict__ Wsl, const float* __restrict__ Wsr,
    unsigned short* __restrict__ Wf1, unsigned short* __restrict__ Wf2) {
    __shared__ unsigned buf[NBUCK][CAPA];
    __shared__ int lcnt[NBUCK];
    __shared__ int goff[NBUCK];
    const int blk = blockIdx.x;
    const int tid = threadIdx.x;
    if (blk < BINA_GRID) {
        binA_body(blk, tid, src, dst, gcur, bins, buf, lcnt, goff);
    } else if (blk < BINA_GRID + CVT_BLOCKS) {
        int t = (blk - BINA_GRID) * 256 + tid;
        const float4* p = (const float4*)x + (size_t)t * 2;
        float4 f0 = p[0], f1 = p[1];
        short8 o;
        o[0] = (short)f2b(f0.x); o[1] = (short)f2b(f0.y);
        o[2] = (short)f2b(f0.z); o[3] = (short)f2b(f0.w);
        o[4] = (short)f2b(f1.x); o[5] = (short)f2b(f1.y);
        o[6] = (short)f2b(f1.z); o[7] = (short)f2b(f1.w);
        *((short8*)xb + t) = o;
        uint2 q;
        q.x = pack4_fp8(f0.x, f0.y, f0.z, f0.w);
        q.y = pack4_fp8(f1.x, f1.y, f1.z, f1.w);
        *((uint2*)xq + t) = q;
    } else {
        int t = (blk - BINA_GRID - CVT_BLOCKS) * 256 + tid;
        if (t >= 2 * 4096) return;
        const int layer = t >> 12;
        const int f = t & 4095;
        const int lane = f & 63;
        const int nt = (f >> 6) & 7;
        const int ks = f >> 9;
        const int col = nt * 16 + (lane & 15);
        const int kb = ks * 32 + ((lane >> 4) << 3);
        short8 o;
#pragma unroll
        for (int e = 0; e < 8; ++e) {
            const int k = kb + e;
            float v;
            if (layer == 0) {
                v = (k < 128) ? W1l[k * 128 + col] : W1r[(k - 128) * 128 + col];
            } else {
                if (col < OC) v = (k < 128) ? Wml[k * OC + col] : Wmr[(k - 128) * OC + col];
                else {
                    int c2 = col - OC;
                    v = (k < 128) ? Wsl[k * OC + c2] : Wsr[(k - 128) * OC + c2];
                }
            }
            o[e] = (short)f2b(v);
        }
        unsigned short* W = (layer == 0) ? Wf1 : Wf2;
        *(short8*)(W + (size_t)f * 8) = o;
    }
}

// ---------------- CSR pass B: scan + hist + place + degree-sorted order ----------------
__global__ __launch_bounds__(256) void k_binB(const int* __restrict__ gcur,
                                              const unsigned* __restrict__ bins,
                                              int* __restrict__ row_ptr,
                                              int* __restrict__ csr,
                                              int* __restrict__ order) {
    __shared__ int lc[512];
    __shared__ int rk[512];
    __shared__ int tsum[256];
    __shared__ int dh[64];
    __shared__ int seg[RCAP];
    __shared__ int sh_bs;
    const int b = blockIdx.x;
    const int t = threadIdx.x;
    const int base = b * BN;
    const int nloc = (NN - base < BN) ? (NN - base) : BN;
    int v = gcur[t * GPAD];
    if (v > RCAP) v = RCAP;
    tsum[t] = v;
    __syncthreads();
    for (int off = 1; off < 256; off <<= 1) {
        int u = (t >= off) ? tsum[t - off] : 0;
        __syncthreads();
        tsum[t] += u;
        __syncthreads();
    }
    if (t == b) sh_bs = tsum[t] - v;
    if (b == 0 && t == 255) row_ptr[NN] = tsum[255];
    lc[t] = 0; lc[t + 256] = 0;
    rk[t] = 0; rk[t + 256] = 0;
    if (t < 64) dh[t] = 0;
    __syncthreads();
    int c = gcur[b * GPAD];
    if (c > RCAP) c = RCAP;
    const unsigned* mb = bins + (size_t)b * RCAP;
    for (int i = t; i < c; i += 256) atomicAdd(&lc[mb[i] >> 17], 1);
    __syncthreads();
    int l0 = lc[2 * t], l1 = lc[2 * t + 1];
    const int d0 = (l0 < 64) ? l0 : 63;
    const int d1 = (l1 < 64) ? l1 : 63;
    if (2 * t < nloc) atomicAdd(&dh[d0], 1);
    if (2 * t + 1 < nloc) atomicAdd(&dh[d1], 1);
    int s = l0 + l1;
    tsum[t] = s;
    __syncthreads();
    for (int off = 1; off < 256; off <<= 1) {
        int u = (t >= off) ? tsum[t - off] : 0;
        __syncthreads();
        tsum[t] += u;
        __syncthreads();
    }
    int run = tsum[t] - s;
    lc[2 * t] = run;
    lc[2 * t + 1] = run + l0;
    if (t < 64) {
        int dv = dh[t];
        int sc = dv;
        for (int off = 1; off < 64; off <<= 1) {
            int u = __shfl_up(sc, off, 64);
            if (t >= off) sc += u;
        }
        dh[t] = sc - dv;
    }
    __syncthreads();
    if (2 * t < nloc) { int p = atomicAdd(&dh[d0], 1); order[base + p] = base + 2 * t; }
    if (2 * t + 1 < nloc) { int p = atomicAdd(&dh[d1], 1); order[base + p] = base + 2 * t + 1; }
    const int bs = sh_bs;
    for (int i = t; i < nloc; i += 256) row_ptr[base + i] = bs + lc[i];
    for (int i = t; i < c; i += 256) {
        unsigned p = mb[i];
        int dl = p >> 17;
        int r = atomicAdd(&rk[dl], 1);
        seg[lc[dl] + r] = (int)(p & 0x1FFFFu);
    }
    __syncthreads();
    for (int i = t; i < c; i += 256) csr[bs + i] = seg[i];
}

// ---------------- gather mean-aggregation (degree-sorted order, branchless bulk) ----------------
// FP8=1: 8-lane slots, 16B/lane (full 128B fp8 row), 8 nodes/wave.
// FP8=0: 16-lane slots, 16B/lane (256B bf16 row), 4 nodes/wave.
template <int FP8>
__global__ __launch_bounds__(256) void k_agg(const unsigned short* __restrict__ feat,
                                             const unsigned char* __restrict__ featq,
                                             const int* __restrict__ row_ptr,
                                             const int* __restrict__ csr,
                                             const int* __restrict__ order,
                                             unsigned short* __restrict__ agg) {
    const int lane = threadIdx.x & 63;
    const int wid = threadIdx.x >> 6;
    if (FP8) {
        const int slot = lane >> 3;
        const int cl = lane & 7;
        const int idx = blockIdx.x * 32 + wid * 8 + slot;
        if (idx >= NN) return;
        const int node = order[idx];
        const int beg = row_ptr[node];
        const int end = row_ptr[node + 1];
        float acc[16];
#pragma unroll
        for (int q = 0; q < 16; ++q) acc[q] = 0.f;
        int j = beg;
        // branchless bulk: 8 independent index loads, then 8 independent row gathers
        for (; j + 8 <= end; j += 8) {
            int sidx[8];
#pragma unroll
            for (int u = 0; u < 8; ++u) sidx[u] = csr[j + u];
            uint4 v[8];
#pragma unroll
            for (int u = 0; u < 8; ++u)
                v[u] = *(const uint4*)(featq + (size_t)sidx[u] * IC + cl * 16);
#pragma unroll
            for (int u = 0; u < 8; ++u) {
                float d[16];
                dec4(v[u].x, d); dec4(v[u].y, d + 4);
                dec4(v[u].z, d + 8); dec4(v[u].w, d + 12);
#pragma unroll
                for (int q = 0; q < 16; ++q) acc[q] += d[q];
            }
        }
        // tail
        for (; j < end; ++j) {
            int s = csr[j];
            uint4 v = *(const uint4*)(featq + (size_t)s * IC + cl * 16);
            float d[16];
            dec4(v.x, d); dec4(v.y, d + 4);
            dec4(v.z, d + 8); dec4(v.w, d + 12);
#pragma unroll
            for (int q = 0; q < 16; ++q) acc[q] += d[q];
        }
        float inv = 1.0f / fmaxf((float)(end - beg), 1.0f);
        short8 o0, o1;
#pragma unroll
        for (int q = 0; q < 8; ++q) o0[q] = (short)f2b(acc[q] * inv);
#pragma unroll
        for (int q = 0; q < 8; ++q) o1[q] = (short)f2b(acc[8 + q] * inv);
        *(short8*)(agg + (size_t)node * IC + cl * 16) = o0;
        *(short8*)(agg + (size_t)node * IC + cl * 16 + 8) = o1;
    } else {
        const int slot = lane >> 4;
        const int cg = lane & 15;
        const int idx = blockIdx.x * 16 + wid * 4 + slot;
        if (idx >= NN) return;
        const int node = order[idx];
        const int beg = row_ptr[node];
        const int end = row_ptr[node + 1];
        float acc[8];
#pragma unroll
        for (int q = 0; q < 8; ++q) acc[q] = 0.f;
        int j = beg;
        for (; j + 8 <= end; j += 8) {
            int sidx[8];
#pragma unroll
            for (int u = 0; u < 8; ++u) sidx[u] = csr[j + u];
            short8 v[8];
#pragma unroll
            for (int u = 0; u < 8; ++u)
                v[u] = *(const short8*)(feat + (size_t)sidx[u] * IC + cg * 8);
#pragma unroll
            for (int u = 0; u < 8; ++u) {
#pragma unroll
                for (int q = 0; q < 8; ++q) acc[q] += b2f((unsigned short)v[u][q]);
            }
        }
        for (; j < end; ++j) {
            int s = csr[j];
            short8 v = *(const short8*)(feat + (size_t)s * IC + cg * 8);
#pragma unroll
            for (int q = 0; q < 8; ++q) acc[q] += b2f((unsigned short)v[q]);
        }
        float inv = 1.0f / fmaxf((float)(end - beg), 1.0f);
        short8 o;
#pragma unroll
        for (int q = 0; q < 8; ++q) o[q] = (short)f2b(acc[q] * inv);
        *(short8*)(agg + (size_t)node * IC + cg * 8) = o;
    }
}

// ---------------- MFMA SAGE GEMM: out = [Agg | X] @ W + b ----------------
template <int MODE>
__global__ __launch_bounds__(256) void k_gemm(
    const unsigned short* __restrict__ Agg, const unsigned short* __restrict__ Xb,
    const unsigned short* __restrict__ Wf,
    const float* __restrict__ bias0, const float* __restrict__ bias1,
    unsigned short* __restrict__ hout, float* __restrict__ out_mu,
    float* __restrict__ out_ls) {
    const int lane = threadIdx.x & 63;
    const int wid = threadIdx.x >> 6;
    const int rowg = blockIdx.x * 128 + wid * 32;
    const int r16 = lane & 15;
    const int k8 = (lane >> 4) * 8;

    __shared__ unsigned short smem[MODE == 0 ? (4 * 32 * LDW) : 16384];
    short8* bsm = (short8*)smem;

    int rA[2];
#pragma unroll
    for (int m = 0; m < 2; ++m) {
        int r = rowg + m * 16 + r16;
        rA[m] = (r < NN) ? r : (NN - 1);
    }

    short8 aF[2][8];
#pragma unroll
    for (int ks = 0; ks < 4; ++ks) {
        aF[0][ks] = *(const short8*)(Agg + (size_t)rA[0] * IC + ks * 32 + k8);
        aF[1][ks] = *(const short8*)(Agg + (size_t)rA[1] * IC + ks * 32 + k8);
    }
#pragma unroll
    for (int ks = 0; ks < 4; ++ks) {
        aF[0][4 + ks] = *(const short8*)(Xb + (size_t)rA[0] * IC + ks * 32 + k8);
        aF[1][4 + ks] = *(const short8*)(Xb + (size_t)rA[1] * IC + ks * 32 + k8);
    }

    const short8* Wg = (const short8*)Wf;
#pragma unroll
    for (int i = 0; i < 8; ++i)
        bsm[i * 256 + threadIdx.x] = Wg[i * 256 + threadIdx.x];

#pragma unroll
    for (int ks = 0; ks < 8; ++ks)
        asm volatile("" :: "v"(aF[0][ks]), "v"(aF[1][ks]));

    __syncthreads();

    f32x4 acc[2][8];
#pragma unroll
    for (int m = 0; m < 2; ++m)
#pragma unroll
        for (int nt = 0; nt < 8; ++nt) acc[m][nt] = (f32x4){0.f, 0.f, 0.f, 0.f};

#pragma unroll
    for (int ks = 0; ks < 4; ++ks) {
        short8 bF[8];
#pragma unroll
        for (int nt = 0; nt < 8; ++nt) bF[nt] = bsm[(ks * 8 + nt) * 64 + lane];
#pragma unroll
        for (int nt = 0; nt < 8; ++nt) {
            acc[0][nt] = __builtin_amdgcn_mfma_f32_16x16x32_bf16(aF[0][ks], bF[nt], acc[0][nt], 0, 0, 0);
            acc[1][nt] = __builtin_amdgcn_mfma_f32_16x16x32_bf16(aF[1][ks], bF[nt], acc[1][nt], 0, 0, 0);
        }
    }
    __syncthreads();
#pragma unroll
    for (int i = 0; i < 8; ++i)
        bsm[i * 256 + threadIdx.x] = Wg[2048 + i * 256 + threadIdx.x];
    __syncthreads();
#pragma unroll
    for (int ks = 4; ks < 8; ++ks) {
        short8 bF[8];
#pragma unroll
        for (int nt = 0; nt < 8; ++nt) bF[nt] = bsm[((ks - 4) * 8 + nt) * 64 + lane];
#pragma unroll
        for (int nt = 0; nt < 8; ++nt) {
            acc[0][nt] = __builtin_amdgcn_mfma_f32_16x16x32_bf16(aF[0][ks], bF[nt], acc[0][nt], 0, 0, 0);
            acc[1][nt] = __builtin_amdgcn_mfma_f32_16x16x32_bf16(aF[1][ks], bF[nt], acc[1][nt], 0, 0, 0);
        }
    }

    const int rbase = (lane >> 4) * 4;
    if (MODE == 0) {
        __syncthreads();
        unsigned short* ws = smem + wid * 32 * LDW;
#pragma unroll
        for (int m = 0; m < 2; ++m) {
#pragma unroll
            for (int nt = 0; nt < 8; ++nt) {
                const int c = nt * 16 + r16;
                const float bv = bias0[c];
#pragma unroll
                for (int q = 0; q < 4; ++q) {
                    float v = fmaxf(acc[m][nt][q] + bv, 0.f);
                    ws[(m * 16 + rbase + q) * LDW + c] = f2b(v);
                }
            }
        }
        __syncthreads();
#pragma unroll
        for (int p = 0; p < 8; ++p) {
            const int rloc = p * 4 + (lane >> 4);
            const int row = rowg + rloc;
            if (row < NN) {
                short8 v = *(const short8*)&ws[rloc * LDW + r16 * 8];
                *(short8*)(hout + (size_t)row * IC + r16 * 8) = v;
            }
        }
    } else {
#pragma unroll
        for (int m = 0; m < 2; ++m) {
#pragma unroll
            for (int nt = 0; nt < 8; ++nt) {
                const int c = nt * 16 + r16;
                const float bv = (c < OC) ? bias0[c] : bias1[c - OC];
#pragma unroll
                for (int q = 0; q < 4; ++q) {
                    const int row = rowg + m * 16 + rbase + q;
                    if (row >= NN) continue;
                    float v = acc[m][nt][q] + bv;
                    if (c < OC) out_mu[(size_t)row * OC + c] = v;
                    else        out_ls[(size_t)row * OC + (c - OC)] = v;
                }
            }
        }
    }
}

extern "C" void kernel_launch(void* const* d_in, const int* in_sizes, int n_in,
                              void* d_out, int out_size, void* d_ws, size_t ws_size,
                              hipStream_t stream) {
    const float* x   = (const float*)d_in[0];
    const int*   ei  = (const int*)d_in[1];
    const float* W1l = (const float*)d_in[2];
    const float* W1r = (const float*)d_in[3];
    const float* b1  = (const float*)d_in[4];
    const float* Wml = (const float*)d_in[5];
    const float* Wmr = (const float*)d_in[6];
    const float* bm  = (const float*)d_in[7];
    const float* Wsl = (const float*)d_in[8];
    const float* Wsr = (const float*)d_in[9];
    const float* bs  = (const float*)d_in[10];

    const int* src = ei;
    const int* dst = ei + NE;

    // workspace layout (bytes)
    char* w = (char*)d_ws;
    unsigned short* xb   = (unsigned short*)(w);                 // 25,600,000
    unsigned short* hb   = (unsigned short*)(w + 25600000);      // 25,600,000
    unsigned short* aggb = (unsigned short*)(w + 51200000);      // 25,600,000
    unsigned short* Wf1  = (unsigned short*)(w + 76800000);      // 65,536
    unsigned short* Wf2  = (unsigned short*)(w + 76865536);      // 65,536
    int* row_ptr  = (int*)(w + 76931072);                        // 400,128 (padded)
    int* csr      = (int*)(w + 77331200);                        // 4,000,000
    int* gcur     = (int*)(w + 81331200);                        // 16,384
    unsigned* bins = (unsigned*)(w + 81347584);                  // 4,718,592
    unsigned char* xq = (unsigned char*)(w + 86066176);          // 12,800,000
    int* order    = (int*)(w + 98866176);                        // 400,000 -> end ~99.3 MB

    float* out_mu = (float*)d_out;
    float* out_ls = out_mu + (size_t)NN * OC;

    const int gemm_grid = (NN + 127) / 128;
    const int agg1_grid = (NN + 31) / 32;
    const int agg2_grid = (NN + 15) / 16;

    // ---- CSR build + conversions (fused front) ----
    hipMemsetAsync(gcur, 0, NBUCK * GPAD * sizeof(int), stream);
    k_front<<<BINA_GRID + CVT_BLOCKS + 32, 256, 0, stream>>>(
        src, dst, gcur, bins, x, xb, xq, W1l, W1r, Wml, Wmr, Wsl, Wsr, Wf1, Wf2);
    k_binB<<<NBUCK, 256, 0, stream>>>(gcur, bins, row_ptr, csr, order);

    // layer 1 (fp8 gather, 8-lane slots)
    k_agg<1><<<agg1_grid, 256, 0, stream>>>(nullptr, xq, row_ptr, csr, order, aggb);
    k_gemm<0><<<gemm_grid, 256, 0, stream>>>(aggb, xb, Wf1, b1, nullptr,
                                             hb, nullptr, nullptr);

    // layer 2 (bf16 gather; shared aggregation feeds mu and logstd)
    k_agg<0><<<agg2_grid, 256, 0, stream>>>(hb, nullptr, row_ptr, csr, order, aggb);
    k_gemm<1><<<gemm_grid, 256, 0, stream>>>(aggb, hb, Wf2, bm, bs,
                                             nullptr, out_mu, out_ls);
}

// Round 14
// 164.905 us; speedup vs baseline: 1.0419x; 1.0419x over previous
//
#include <hip/hip_runtime.h>

#define NN 100000
#define IC 128
#define OC 64
#define NE 1000000

#define NBUCK 256
#define BN 392          // nodes per bucket; 256*392 = 100352 >= NN
#define RCAP 4608       // bucket region capacity (mean 3906, +11 sigma)
#define EPB 2048        // edges per binning block
#define CAPA 24         // LDS buffer entries per bucket per block
#define GPAD 16         // gcur padding: one counter per 64B line
#define LDW 136         // epilogue LDS row stride (128 + 8 pad), ushorts
#define BINA_GRID 489   // ceil(NE/EPB)
#define CVT_BLOCKS 6250 // NN*IC/8/256

typedef __attribute__((ext_vector_type(8))) short short8;
typedef __attribute__((ext_vector_type(4))) float f32x4;

static __device__ __forceinline__ float b2f(unsigned short u) {
    unsigned v = ((unsigned)u) << 16;
    float f;
    __builtin_memcpy(&f, &v, 4);
    return f;
}
static __device__ __forceinline__ unsigned short f2b(float f) {
    unsigned u;
    __builtin_memcpy(&u, &f, 4);
    u += 0x7fff + ((u >> 16) & 1);
    return (unsigned short)(u >> 16);
}

// ---------------- fp8 e4m3 encode/decode (hw cvt if available, manual fallback) ----------------
#if defined(__has_builtin)
#if __has_builtin(__builtin_amdgcn_cvt_pk_fp8_f32) && __has_builtin(__builtin_amdgcn_cvt_pk_f32_fp8)
#define HW_FP8 1
#endif
#endif

static __device__ __forceinline__ unsigned f2q1(float f) {  // manual e4m3fn, FTZ
    unsigned u;
    __builtin_memcpy(&u, &f, 4);
    unsigned s = (u >> 24) & 0x80u;
    unsigned a = u & 0x7FFFFFFFu;
    if (a < 0x3C000000u) return s;
    if (a < 0x3C800000u) return s | 0x08u;
    if (a >= 0x43E00000u) return s | 0x7Eu;
    a += 0x7FFFFu + ((a >> 20) & 1u);
    unsigned e = (a >> 23) - 120u;
    unsigned m = (a >> 20) & 7u;
    unsigned c = (e << 3) | m;
    if (c > 0x7Eu) c = 0x7Eu;
    return s | c;
}
static __device__ __forceinline__ float q1f(unsigned q) {
    unsigned em = q & 0x7Fu;
    unsigned s = (q & 0x80u) << 24;
    unsigned u = (em >= 8u) ? (s | (((em >> 3) + 120u) << 23) | ((em & 7u) << 20)) : s;
    float f;
    __builtin_memcpy(&f, &u, 4);
    return f;
}

static __device__ __forceinline__ unsigned pack4_fp8(float a, float b, float c, float d) {
#ifdef HW_FP8
    int r = __builtin_amdgcn_cvt_pk_fp8_f32(a, b, 0, false);
    r = __builtin_amdgcn_cvt_pk_fp8_f32(c, d, r, true);
    return (unsigned)r;
#else
    return f2q1(a) | (f2q1(b) << 8) | (f2q1(c) << 16) | (f2q1(d) << 24);
#endif
}
static __device__ __forceinline__ void dec4(unsigned w, float* o) {
#ifdef HW_FP8
    auto p0 = __builtin_amdgcn_cvt_pk_f32_fp8((int)w, false);
    auto p1 = __builtin_amdgcn_cvt_pk_f32_fp8((int)w, true);
    o[0] = p0[0]; o[1] = p0[1]; o[2] = p1[0]; o[3] = p1[1];
#else
#pragma unroll
    for (int q = 0; q < 4; ++q) o[q] = q1f((w >> (8 * q)) & 0xFFu);
#endif
}

// ---------------- CSR pass A body: partition edges into 256 dst-range buckets ----------------
__device__ __forceinline__ void binA_body(int blk, int t,
                                          const int* __restrict__ src,
                                          const int* __restrict__ dst,
                                          int* __restrict__ gcur,
                                          unsigned* __restrict__ bins,
                                          unsigned (*buf)[CAPA], int* lcnt, int* goff) {
    lcnt[t] = 0;
    __syncthreads();
    const int e0 = blk * EPB;
#pragma unroll
    for (int q = 0; q < EPB / 256; ++q) {
        int e = e0 + q * 256 + t;
        if (e < NE) {
            int d = dst[e];
            int s = src[e];
            int b = d / BN;
            unsigned packed = ((unsigned)(d - b * BN) << 17) | (unsigned)s;
            int idx = atomicAdd(&lcnt[b], 1);
            if (idx < CAPA) {
                buf[b][idx] = packed;
            } else {
                int g = atomicAdd(&gcur[b * GPAD], 1);
                if (g < RCAP) bins[(size_t)b * RCAP + g] = packed;
            }
        }
    }
    __syncthreads();
    int c = lcnt[t];
    if (c > CAPA) c = CAPA;
    if (c > 0) goff[t] = atomicAdd(&gcur[t * GPAD], c);
    __syncthreads();
    const int wid = t >> 6, lane = t & 63;
    for (int b = wid * 64; b < wid * 64 + 64; ++b) {
        int cb = lcnt[b];
        if (cb > CAPA) cb = CAPA;
        if (lane < cb) {
            int g = goff[b] + lane;
            if (g < RCAP) bins[(size_t)b * RCAP + g] = buf[b][lane];
        }
    }
}

// ---------------- fused front kernel: binA | x->bf16+fp8 | weight prep ----------------
__global__ __launch_bounds__(256) void k_front(
    const int* __restrict__ src, const int* __restrict__ dst,
    int* __restrict__ gcur, unsigned* __restrict__ bins,
    const float* __restrict__ x, unsigned short* __restrict__ xb,
    unsigned char* __restrict__ xq,
    const float* __restrict__ W1l, const float* __restrict__ W1r,
    const float* __restrict__ Wml, const float* __restrict__ Wmr,
    const float* __restrict__ Wsl, const float* __restrict__ Wsr,
    unsigned short* __restrict__ Wf1, unsigned short* __restrict__ Wf2) {
    __shared__ unsigned buf[NBUCK][CAPA];
    __shared__ int lcnt[NBUCK];
    __shared__ int goff[NBUCK];
    const int blk = blockIdx.x;
    const int tid = threadIdx.x;
    if (blk < BINA_GRID) {
        binA_body(blk, tid, src, dst, gcur, bins, buf, lcnt, goff);
    } else if (blk < BINA_GRID + CVT_BLOCKS) {
        int t = (blk - BINA_GRID) * 256 + tid;
        const float4* p = (const float4*)x + (size_t)t * 2;
        float4 f0 = p[0], f1 = p[1];
        short8 o;
        o[0] = (short)f2b(f0.x); o[1] = (short)f2b(f0.y);
        o[2] = (short)f2b(f0.z); o[3] = (short)f2b(f0.w);
        o[4] = (short)f2b(f1.x); o[5] = (short)f2b(f1.y);
        o[6] = (short)f2b(f1.z); o[7] = (short)f2b(f1.w);
        *((short8*)xb + t) = o;
        uint2 q;
        q.x = pack4_fp8(f0.x, f0.y, f0.z, f0.w);
        q.y = pack4_fp8(f1.x, f1.y, f1.z, f1.w);
        *((uint2*)xq + t) = q;
    } else {
        int t = (blk - BINA_GRID - CVT_BLOCKS) * 256 + tid;
        if (t >= 2 * 4096) return;
        const int layer = t >> 12;
        const int f = t & 4095;
        const int lane = f & 63;
        const int nt = (f >> 6) & 7;
        const int ks = f >> 9;
        const int col = nt * 16 + (lane & 15);
        const int kb = ks * 32 + ((lane >> 4) << 3);
        short8 o;
#pragma unroll
        for (int e = 0; e < 8; ++e) {
            const int k = kb + e;
            float v;
            if (layer == 0) {
                v = (k < 128) ? W1l[k * 128 + col] : W1r[(k - 128) * 128 + col];
            } else {
                if (col < OC) v = (k < 128) ? Wml[k * OC + col] : Wmr[(k - 128) * OC + col];
                else {
                    int c2 = col - OC;
                    v = (k < 128) ? Wsl[k * OC + c2] : Wsr[(k - 128) * OC + c2];
                }
            }
            o[e] = (short)f2b(v);
        }
        unsigned short* W = (layer == 0) ? Wf1 : Wf2;
        *(short8*)(W + (size_t)f * 8) = o;
    }
}

// ---------------- CSR pass B: scan + hist + place + degree-sorted order ----------------
__global__ __launch_bounds__(256) void k_binB(const int* __restrict__ gcur,
                                              const unsigned* __restrict__ bins,
                                              int* __restrict__ row_ptr,
                                              int* __restrict__ csr,
                                              int* __restrict__ order) {
    __shared__ int lc[512];
    __shared__ int rk[512];
    __shared__ int tsum[256];
    __shared__ int dh[64];
    __shared__ int seg[RCAP];
    __shared__ int sh_bs;
    const int b = blockIdx.x;
    const int t = threadIdx.x;
    const int base = b * BN;
    const int nloc = (NN - base < BN) ? (NN - base) : BN;
    int v = gcur[t * GPAD];
    if (v > RCAP) v = RCAP;
    tsum[t] = v;
    __syncthreads();
    for (int off = 1; off < 256; off <<= 1) {
        int u = (t >= off) ? tsum[t - off] : 0;
        __syncthreads();
        tsum[t] += u;
        __syncthreads();
    }
    if (t == b) sh_bs = tsum[t] - v;
    if (b == 0 && t == 255) row_ptr[NN] = tsum[255];
    lc[t] = 0; lc[t + 256] = 0;
    rk[t] = 0; rk[t + 256] = 0;
    if (t < 64) dh[t] = 0;
    __syncthreads();
    int c = gcur[b * GPAD];
    if (c > RCAP) c = RCAP;
    const unsigned* mb = bins + (size_t)b * RCAP;
    for (int i = t; i < c; i += 256) atomicAdd(&lc[mb[i] >> 17], 1);
    __syncthreads();
    int l0 = lc[2 * t], l1 = lc[2 * t + 1];
    const int d0 = (l0 < 64) ? l0 : 63;
    const int d1 = (l1 < 64) ? l1 : 63;
    if (2 * t < nloc) atomicAdd(&dh[d0], 1);
    if (2 * t + 1 < nloc) atomicAdd(&dh[d1], 1);
    int s = l0 + l1;
    tsum[t] = s;
    __syncthreads();
    for (int off = 1; off < 256; off <<= 1) {
        int u = (t >= off) ? tsum[t - off] : 0;
        __syncthreads();
        tsum[t] += u;
        __syncthreads();
    }
    int run = tsum[t] - s;
    lc[2 * t] = run;
    lc[2 * t + 1] = run + l0;
    if (t < 64) {
        int dv = dh[t];
        int sc = dv;
        for (int off = 1; off < 64; off <<= 1) {
            int u = __shfl_up(sc, off, 64);
            if (t >= off) sc += u;
        }
        dh[t] = sc - dv;
    }
    __syncthreads();
    if (2 * t < nloc) { int p = atomicAdd(&dh[d0], 1); order[base + p] = base + 2 * t; }
    if (2 * t + 1 < nloc) { int p = atomicAdd(&dh[d1], 1); order[base + p] = base + 2 * t + 1; }
    const int bs = sh_bs;
    for (int i = t; i < nloc; i += 256) row_ptr[base + i] = bs + lc[i];
    for (int i = t; i < c; i += 256) {
        unsigned p = mb[i];
        int dl = p >> 17;
        int r = atomicAdd(&rk[dl], 1);
        seg[lc[dl] + r] = (int)(p & 0x1FFFFu);
    }
    __syncthreads();
    for (int i = t; i < c; i += 256) csr[bs + i] = seg[i];
}

// ---------------- gather mean-aggregation: clamped full batches + index prefetch ----------------
// FP8=1: 8-lane slots, 16B/lane (full 128B fp8 row), 8 nodes/wave.
// FP8=0: 16-lane slots, 16B/lane (256B bf16 row), 4 nodes/wave.
// All batches are full 8-wide (indices clamped to last edge); accumulate masked.
// Next batch's indices load while current batch's gathers are in flight.
template <int FP8>
__global__ __launch_bounds__(256) void k_agg(const unsigned short* __restrict__ feat,
                                             const unsigned char* __restrict__ featq,
                                             const int* __restrict__ row_ptr,
                                             const int* __restrict__ csr,
                                             const int* __restrict__ order,
                                             unsigned short* __restrict__ agg) {
    const int lane = threadIdx.x & 63;
    const int wid = threadIdx.x >> 6;
    if (FP8) {
        const int slot = lane >> 3;
        const int cl = lane & 7;
        const int idx = blockIdx.x * 32 + wid * 8 + slot;
        if (idx >= NN) return;
        const int node = order[idx];
        const int beg = row_ptr[node];
        const int end = row_ptr[node + 1];
        if (beg == end) {
            short8 z = {0, 0, 0, 0, 0, 0, 0, 0};
            *(short8*)(agg + (size_t)node * IC + cl * 16) = z;
            *(short8*)(agg + (size_t)node * IC + cl * 16 + 8) = z;
            return;
        }
        const int last = end - 1;
        float acc[16];
#pragma unroll
        for (int q = 0; q < 16; ++q) acc[q] = 0.f;
        int sidx[8];
#pragma unroll
        for (int u = 0; u < 8; ++u) {
            int jj = beg + u;
            sidx[u] = csr[(jj < last) ? jj : last];
        }
        for (int j = beg; j < end; j += 8) {
            uint4 v[8];
#pragma unroll
            for (int u = 0; u < 8; ++u)
                v[u] = *(const uint4*)(featq + (size_t)sidx[u] * IC + cl * 16);
            // prefetch next batch's indices (overlaps gather latency)
            const int jn = j + 8;
            if (jn < end) {
#pragma unroll
                for (int u = 0; u < 8; ++u) {
                    int jj = jn + u;
                    sidx[u] = csr[(jj < last) ? jj : last];
                }
            }
#pragma unroll
            for (int u = 0; u < 8; ++u) {
                const bool ok = (j + u) < end;
                float d[16];
                dec4(v[u].x, d); dec4(v[u].y, d + 4);
                dec4(v[u].z, d + 8); dec4(v[u].w, d + 12);
#pragma unroll
                for (int q = 0; q < 16; ++q) acc[q] += ok ? d[q] : 0.f;
            }
        }
        float inv = 1.0f / (float)(end - beg);
        short8 o0, o1;
#pragma unroll
        for (int q = 0; q < 8; ++q) o0[q] = (short)f2b(acc[q] * inv);
#pragma unroll
        for (int q = 0; q < 8; ++q) o1[q] = (short)f2b(acc[8 + q] * inv);
        *(short8*)(agg + (size_t)node * IC + cl * 16) = o0;
        *(short8*)(agg + (size_t)node * IC + cl * 16 + 8) = o1;
    } else {
        const int slot = lane >> 4;
        const int cg = lane & 15;
        const int idx = blockIdx.x * 16 + wid * 4 + slot;
        if (idx >= NN) return;
        const int node = order[idx];
        const int beg = row_ptr[node];
        const int end = row_ptr[node + 1];
        if (beg == end) {
            short8 z = {0, 0, 0, 0, 0, 0, 0, 0};
            *(short8*)(agg + (size_t)node * IC + cg * 8) = z;
            return;
        }
        const int last = end - 1;
        float acc[8];
#pragma unroll
        for (int q = 0; q < 8; ++q) acc[q] = 0.f;
        int sidx[8];
#pragma unroll
        for (int u = 0; u < 8; ++u) {
            int jj = beg + u;
            sidx[u] = csr[(jj < last) ? jj : last];
        }
        for (int j = beg; j < end; j += 8) {
            short8 v[8];
#pragma unroll
            for (int u = 0; u < 8; ++u)
                v[u] = *(const short8*)(feat + (size_t)sidx[u] * IC + cg * 8);
            const int jn = j + 8;
            if (jn < end) {
#pragma unroll
                for (int u = 0; u < 8; ++u) {
                    int jj = jn + u;
                    sidx[u] = csr[(jj < last) ? jj : last];
                }
            }
#pragma unroll
            for (int u = 0; u < 8; ++u) {
                const bool ok = (j + u) < end;
#pragma unroll
                for (int q = 0; q < 8; ++q)
                    acc[q] += ok ? b2f((unsigned short)v[u][q]) : 0.f;
            }
        }
        float inv = 1.0f / (float)(end - beg);
        short8 o;
#pragma unroll
        for (int q = 0; q < 8; ++q) o[q] = (short)f2b(acc[q] * inv);
        *(short8*)(agg + (size_t)node * IC + cg * 8) = o;
    }
}

// ---------------- MFMA SAGE GEMM: out = [Agg | X] @ W + b ----------------
template <int MODE>
__global__ __launch_bounds__(256) void k_gemm(
    const unsigned short* __restrict__ Agg, const unsigned short* __restrict__ Xb,
    const unsigned short* __restrict__ Wf,
    const float* __restrict__ bias0, const float* __restrict__ bias1,
    unsigned short* __restrict__ hout, float* __restrict__ out_mu,
    float* __restrict__ out_ls) {
    const int lane = threadIdx.x & 63;
    const int wid = threadIdx.x >> 6;
    const int rowg = blockIdx.x * 128 + wid * 32;
    const int r16 = lane & 15;
    const int k8 = (lane >> 4) * 8;

    __shared__ unsigned short smem[MODE == 0 ? (4 * 32 * LDW) : 16384];
    short8* bsm = (short8*)smem;

    int rA[2];
#pragma unroll
    for (int m = 0; m < 2; ++m) {
        int r = rowg + m * 16 + r16;
        rA[m] = (r < NN) ? r : (NN - 1);
    }

    short8 aF[2][8];
#pragma unroll
    for (int ks = 0; ks < 4; ++ks) {
        aF[0][ks] = *(const short8*)(Agg + (size_t)rA[0] * IC + ks * 32 + k8);
        aF[1][ks] = *(const short8*)(Agg + (size_t)rA[1] * IC + ks * 32 + k8);
    }
#pragma unroll
    for (int ks = 0; ks < 4; ++ks) {
        aF[0][4 + ks] = *(const short8*)(Xb + (size_t)rA[0] * IC + ks * 32 + k8);
        aF[1][4 + ks] = *(const short8*)(Xb + (size_t)rA[1] * IC + ks * 32 + k8);
    }

    const short8* Wg = (const short8*)Wf;
#pragma unroll
    for (int i = 0; i < 8; ++i)
        bsm[i * 256 + threadIdx.x] = Wg[i * 256 + threadIdx.x];

#pragma unroll
    for (int ks = 0; ks < 8; ++ks)
        asm volatile("" :: "v"(aF[0][ks]), "v"(aF[1][ks]));

    __syncthreads();

    f32x4 acc[2][8];
#pragma unroll
    for (int m = 0; m < 2; ++m)
#pragma unroll
        for (int nt = 0; nt < 8; ++nt) acc[m][nt] = (f32x4){0.f, 0.f, 0.f, 0.f};

#pragma unroll
    for (int ks = 0; ks < 4; ++ks) {
        short8 bF[8];
#pragma unroll
        for (int nt = 0; nt < 8; ++nt) bF[nt] = bsm[(ks * 8 + nt) * 64 + lane];
#pragma unroll
        for (int nt = 0; nt < 8; ++nt) {
            acc[0][nt] = __builtin_amdgcn_mfma_f32_16x16x32_bf16(aF[0][ks], bF[nt], acc[0][nt], 0, 0, 0);
            acc[1][nt] = __builtin_amdgcn_mfma_f32_16x16x32_bf16(aF[1][ks], bF[nt], acc[1][nt], 0, 0, 0);
        }
    }
    __syncthreads();
#pragma unroll
    for (int i = 0; i < 8; ++i)
        bsm[i * 256 + threadIdx.x] = Wg[2048 + i * 256 + threadIdx.x];
    __syncthreads();
#pragma unroll
    for (int ks = 4; ks < 8; ++ks) {
        short8 bF[8];
#pragma unroll
        for (int nt = 0; nt < 8; ++nt) bF[nt] = bsm[((ks - 4) * 8 + nt) * 64 + lane];
#pragma unroll
        for (int nt = 0; nt < 8; ++nt) {
            acc[0][nt] = __builtin_amdgcn_mfma_f32_16x16x32_bf16(aF[0][ks], bF[nt], acc[0][nt], 0, 0, 0);
            acc[1][nt] = __builtin_amdgcn_mfma_f32_16x16x32_bf16(aF[1][ks], bF[nt], acc[1][nt], 0, 0, 0);
        }
    }

    const int rbase = (lane >> 4) * 4;
    if (MODE == 0) {
        __syncthreads();
        unsigned short* ws = smem + wid * 32 * LDW;
#pragma unroll
        for (int m = 0; m < 2; ++m) {
#pragma unroll
            for (int nt = 0; nt < 8; ++nt) {
                const int c = nt * 16 + r16;
                const float bv = bias0[c];
#pragma unroll
                for (int q = 0; q < 4; ++q) {
                    float v = fmaxf(acc[m][nt][q] + bv, 0.f);
                    ws[(m * 16 + rbase + q) * LDW + c] = f2b(v);
                }
            }
        }
        __syncthreads();
#pragma unroll
        for (int p = 0; p < 8; ++p) {
            const int rloc = p * 4 + (lane >> 4);
            const int row = rowg + rloc;
            if (row < NN) {
                short8 v = *(const short8*)&ws[rloc * LDW + r16 * 8];
                *(short8*)(hout + (size_t)row * IC + r16 * 8) = v;
            }
        }
    } else {
#pragma unroll
        for (int m = 0; m < 2; ++m) {
#pragma unroll
            for (int nt = 0; nt < 8; ++nt) {
                const int c = nt * 16 + r16;
                const float bv = (c < OC) ? bias0[c] : bias1[c - OC];
#pragma unroll
                for (int q = 0; q < 4; ++q) {
                    const int row = rowg + m * 16 + rbase + q;
                    if (row >= NN) continue;
                    float v = acc[m][nt][q] + bv;
                    if (c < OC) out_mu[(size_t)row * OC + c] = v;
                    else        out_ls[(size_t)row * OC + (c - OC)] = v;
                }
            }
        }
    }
}

extern "C" void kernel_launch(void* const* d_in, const int* in_sizes, int n_in,
                              void* d_out, int out_size, void* d_ws, size_t ws_size,
                              hipStream_t stream) {
    const float* x   = (const float*)d_in[0];
    const int*   ei  = (const int*)d_in[1];
    const float* W1l = (const float*)d_in[2];
    const float* W1r = (const float*)d_in[3];
    const float* b1  = (const float*)d_in[4];
    const float* Wml = (const float*)d_in[5];
    const float* Wmr = (const float*)d_in[6];
    const float* bm  = (const float*)d_in[7];
    const float* Wsl = (const float*)d_in[8];
    const float* Wsr = (const float*)d_in[9];
    const float* bs  = (const float*)d_in[10];

    const int* src = ei;
    const int* dst = ei + NE;

    // workspace layout (bytes)
    char* w = (char*)d_ws;
    unsigned short* xb   = (unsigned short*)(w);                 // 25,600,000
    unsigned short* hb   = (unsigned short*)(w + 25600000);      // 25,600,000
    unsigned short* aggb = (unsigned short*)(w + 51200000);      // 25,600,000
    unsigned short* Wf1  = (unsigned short*)(w + 76800000);      // 65,536
    unsigned short* Wf2  = (unsigned short*)(w + 76865536);      // 65,536
    int* row_ptr  = (int*)(w + 76931072);                        // 400,128 (padded)
    int* csr      = (int*)(w + 77331200);                        // 4,000,000
    int* gcur     = (int*)(w + 81331200);                        // 16,384
    unsigned* bins = (unsigned*)(w + 81347584);                  // 4,718,592
    unsigned char* xq = (unsigned char*)(w + 86066176);          // 12,800,000
    int* order    = (int*)(w + 98866176);                        // 400,000 -> end ~99.3 MB

    float* out_mu = (float*)d_out;
    float* out_ls = out_mu + (size_t)NN * OC;

    const int gemm_grid = (NN + 127) / 128;
    const int agg1_grid = (NN + 31) / 32;
    const int agg2_grid = (NN + 15) / 16;

    // ---- CSR build + conversions (fused front) ----
    hipMemsetAsync(gcur, 0, NBUCK * GPAD * sizeof(int), stream);
    k_front<<<BINA_GRID + CVT_BLOCKS + 32, 256, 0, stream>>>(
        src, dst, gcur, bins, x, xb, xq, W1l, W1r, Wml, Wmr, Wsl, Wsr, Wf1, Wf2);
    k_binB<<<NBUCK, 256, 0, stream>>>(gcur, bins, row_ptr, csr, order);

    // layer 1 (fp8 gather, 8-lane slots)
    k_agg<1><<<agg1_grid, 256, 0, stream>>>(nullptr, xq, row_ptr, csr, order, aggb);
    k_gemm<0><<<gemm_grid, 256, 0, stream>>>(aggb, xb, Wf1, b1, nullptr,
                                             hb, nullptr, nullptr);

    // layer 2 (bf16 gather; shared aggregation feeds mu and logstd)
    k_agg<0><<<agg2_grid, 256, 0, stream>>>(hb, nullptr, row_ptr, csr, order, aggb);
    k_gemm<1><<<gemm_grid, 256, 0, stream>>>(aggb, hb, Wf2, bm, bs,
                                             nullptr, out_mu, out_ls);
}